// Round 1
// baseline (387.056 us; speedup 1.0000x reference)
//
#include <hip/hip_runtime.h>

#define BATCH 65536
#define SEQ   64
#define INF   16
#define HS    10
#define UPL   3     // units per lane (H padded to 12 = 4 lanes * 3)
#define OUTF  5
#define KSC   2.8853900817779268f   // 2*log2(e): tanh(t)=1-2/(exp2(KSC*t)+1)

// Pin a float into a VGPR: opaque to the optimizer -> defeats
// rematerialization/sinking of the originating load into the hot loop.
#define PIN(v) asm volatile("" : "+v"(v))

// Quad-lane xor exchange via DPP quad_perm: pure VALU (no LDS pipe, no
// address math, no lgkmcnt wait). sel[i] = i^m encoded 2 bits/lane.
//   xor1 -> [1,0,3,2] = 0xB1, xor2 -> [2,3,0,1] = 0x4E, xor3 -> [3,2,1,0] = 0x1B
template <int C>
__device__ __forceinline__ float qp(float v) {
    return __builtin_bit_cast(float,
        __builtin_amdgcn_update_dpp(0, __builtin_bit_cast(int, v),
                                    C, 0xF, 0xF, true));
}
template <int C>
__device__ __forceinline__ float4 qp4(float4 v) {
    return make_float4(qp<C>(v.x), qp<C>(v.y), qp<C>(v.z), qp<C>(v.w));
}

// Quad-per-row, partitioned by HIDDEN UNIT:
//  - lane j loads x cols 4j..4j+3 (wave = 16 rows x 64B full lines, coalesced)
//  - 3 DPP quad_perm broadcasts give every lane all 16 x values; feed-forward
//    path only, nothing cross-lane on the h_{t-1}->h_t serial chain
//  - lane j owns units 3j..3j+2: 48 FMA + 3 exp + 3 rcp per step
//  - W1/b1 pre-scaled by 2*log2(e): serial chain is fma->exp2->add->rcp->fma
__global__ __launch_bounds__(256, 4) void rnn_fused(
    const float* __restrict__ x,  const float* __restrict__ W1,
    const float* __restrict__ b1, const float* __restrict__ W2,
    const float* __restrict__ b2, float* __restrict__ out)
{
    const int g   = blockIdx.x * 256 + threadIdx.x;
    const int row = g >> 2;     // batch row
    const int j   = g & 3;      // quad lane

    // Weights for this lane's units, ordered by DPP-arrival group:
    // group m supplies cols 4*(j^m)+k.  wl[m][k][u] = KSC*W1[col][hu],
    // 0-padded for hu>=10 (clamped address, zeroed value).
    float wl[4][4][UPL];
    float bl[UPL];
#pragma unroll
    for (int u = 0; u < UPL; ++u) {
        const int hu = UPL * j + u;
        const int hc = (hu < HS) ? hu : 0;
        const bool ok = (hu < HS);
        bl[u] = ok ? KSC * b1[hc] : 0.0f;
#pragma unroll
        for (int m = 0; m < 4; ++m) {
            const int lm = j ^ m;
#pragma unroll
            for (int k = 0; k < 4; ++k) {
                const int col = 4 * lm + k;
                wl[m][k][u] = ok ? KSC * W1[col * HS + hc] : 0.0f;
            }
        }
    }
#pragma unroll
    for (int m = 0; m < 4; ++m)
#pragma unroll
        for (int k = 0; k < 4; ++k)
#pragma unroll
            for (int u = 0; u < UPL; ++u) { PIN(wl[m][k][u]); }
#pragma unroll
    for (int u = 0; u < UPL; ++u) { PIN(bl[u]); }

    float h[UPL];
#pragma unroll
    for (int u = 0; u < UPL; ++u) h[u] = 0.0f;

    // lane j's float4 of step s: x[row][s][4j..4j+3]
    const float4* __restrict__ xr =
        reinterpret_cast<const float4*>(x) + (size_t)row * (SEQ * 4) + j;

    // depth-4 register prefetch (1 KB/wave/slot)
    float4 buf[4];
#pragma unroll
    for (int r = 0; r < 4; ++r) buf[r] = xr[r * 4];

#define STEP(S, PF)                                                          \
    {                                                                        \
        const int slot = (S) & 3;                                            \
        const float4 g0 = buf[slot];                                         \
        if (PF) buf[slot] = xr[((S) + 4) * 4];                               \
        const float4 g1 = qp4<0xB1>(g0);                                     \
        const float4 g2 = qp4<0x4E>(g0);                                     \
        const float4 g3 = qp4<0x1B>(g0);                                     \
        _Pragma("unroll")                                                    \
        for (int u = 0; u < UPL; ++u) {                                      \
            /* 4 parallel FMA chains (depth 4) -> 2-level tree combine */    \
            float p0 = fmaf(g0.x, wl[0][0][u], bl[u]);                       \
            p0 = fmaf(g0.y, wl[0][1][u], p0);                                \
            p0 = fmaf(g0.z, wl[0][2][u], p0);                                \
            p0 = fmaf(g0.w, wl[0][3][u], p0);                                \
            float p1 = g1.x * wl[1][0][u];                                   \
            p1 = fmaf(g1.y, wl[1][1][u], p1);                                \
            p1 = fmaf(g1.z, wl[1][2][u], p1);                                \
            p1 = fmaf(g1.w, wl[1][3][u], p1);                                \
            float p2 = g2.x * wl[2][0][u];                                   \
            p2 = fmaf(g2.y, wl[2][1][u], p2);                                \
            p2 = fmaf(g2.z, wl[2][2][u], p2);                                \
            p2 = fmaf(g2.w, wl[2][3][u], p2);                                \
            float p3 = g3.x * wl[3][0][u];                                   \
            p3 = fmaf(g3.y, wl[3][1][u], p3);                                \
            p3 = fmaf(g3.z, wl[3][2][u], p3);                                \
            p3 = fmaf(g3.w, wl[3][3][u], p3);                                \
            const float aK = (p0 + p1) + (p2 + p3);   /* = KSC*(x@W1+b1) */  \
            /* tanh(h+a) = 1 - 2/(exp2(KSC*h + aK) + 1); rcp ~2-3ulp */      \
            const float e = __builtin_amdgcn_exp2f(fmaf(KSC, h[u], aK));     \
            h[u] = fmaf(-2.0f, __builtin_amdgcn_rcpf(e + 1.0f), 1.0f);       \
        }                                                                    \
    }

    // main loop: unconditional prefetch; tail: no prefetch (no clamp math)
#pragma unroll 4
    for (int s = 0; s < SEQ - 4; ++s) STEP(s, true);
#pragma unroll
    for (int s = SEQ - 4; s < SEQ; ++s) STEP(s, false);
#undef STEP

    // epilogue: y = sigmoid(h @ W2 + b2); partial over this lane's units,
    // then quad butterfly all-reduce via DPP (padded units have h==0).
    float y[OUTF];
#pragma unroll
    for (int o = 0; o < OUTF; ++o) y[o] = 0.0f;
#pragma unroll
    for (int u = 0; u < UPL; ++u) {
        const int hu = UPL * j + u;
        const float* w2r = W2 + (size_t)((hu < HS) ? hu : 0) * OUTF;
#pragma unroll
        for (int o = 0; o < OUTF; ++o)
            y[o] = fmaf(h[u], w2r[o], y[o]);
    }
#pragma unroll
    for (int o = 0; o < OUTF; ++o) y[o] += qp<0xB1>(y[o]);
#pragma unroll
    for (int o = 0; o < OUTF; ++o) y[o] += qp<0x4E>(y[o]);
#pragma unroll
    for (int o = 0; o < OUTF; ++o)
        y[o] = __builtin_amdgcn_rcpf(1.0f + __expf(-(y[o] + b2[o])));

    float* op = out + (size_t)row * OUTF;
    op[j] = y[j];
    if (j == 0) op[4] = y[4];
}

extern "C" void kernel_launch(void* const* d_in, const int* in_sizes, int n_in,
                              void* d_out, int out_size, void* d_ws, size_t ws_size,
                              hipStream_t stream) {
    const float* x  = (const float*)d_in[0];
    const float* W1 = (const float*)d_in[1];
    const float* b1 = (const float*)d_in[2];
    const float* W2 = (const float*)d_in[3];
    const float* b2 = (const float*)d_in[4];
    float* out = (float*)d_out;

    rnn_fused<<<(BATCH * 4) / 256, 256, 0, stream>>>(x, W1, b1, W2, b2, out);
}

// Round 2
// 348.739 us; speedup vs baseline: 1.1099x; 1.1099x over previous
//
#include <hip/hip_runtime.h>

#define BATCH 65536
#define SEQ   64
#define INF   16
#define HS    10
#define UPL   3     // units per lane (H padded to 12 = 4 lanes * 3)
#define OUTF  5
#define KSC   2.8853900817779268f   // 2*log2(e): tanh(t)=1-2/(exp2(KSC*t)+1)
#define PFD   8     // prefetch depth (x float4 slots per thread)

// Pin a float into a VGPR: opaque to the optimizer -> defeats
// rematerialization/sinking of the originating load into the hot loop.
#define PIN(v) asm volatile("" : "+v"(v))

// ext_vector float4 (class-type float4 can't take __builtin_nontemporal_load)
typedef float f4v __attribute__((ext_vector_type(4)));

// Quad-lane xor exchange via DPP quad_perm: pure VALU (no LDS pipe, no
// address math, no lgkmcnt wait). sel[i] = i^m encoded 2 bits/lane.
//   xor1 -> [1,0,3,2] = 0xB1, xor2 -> [2,3,0,1] = 0x4E, xor3 -> [3,2,1,0] = 0x1B
template <int C>
__device__ __forceinline__ float qp(float v) {
    return __builtin_bit_cast(float,
        __builtin_amdgcn_update_dpp(0, __builtin_bit_cast(int, v),
                                    C, 0xF, 0xF, true));
}
template <int C>
__device__ __forceinline__ f4v qp4(f4v v) {
    f4v r;
    r.x = qp<C>(v.x); r.y = qp<C>(v.y); r.z = qp<C>(v.z); r.w = qp<C>(v.w);
    return r;
}

// Quad-per-row, partitioned by HIDDEN UNIT:
//  - lane j loads x cols 4j..4j+3 (wave = 16 rows x 64B full lines, coalesced)
//  - nontemporal: x is a 256 MiB read-once stream >> 32 MiB L2 -> nt bit,
//    don't allocate dead lines into L2
//  - depth-8 register prefetch: vmcnt(7) keeps ~7 KB/wave in flight; 8-step
//    slack ~2x the ~900 cy HBM-miss latency (depth-4 was marginal)
//  - 3 DPP quad_perm broadcasts give every lane all 16 x values; feed-forward
//    path only, nothing cross-lane on the h_{t-1}->h_t serial chain
//  - lane j owns units 3j..3j+2: 48 FMA + 3 exp + 3 rcp per step
//  - W1/b1 pre-scaled by 2*log2(e): serial chain is fma->exp2->add->rcp->fma
__global__ __launch_bounds__(256, 4) void rnn_fused(
    const float* __restrict__ x,  const float* __restrict__ W1,
    const float* __restrict__ b1, const float* __restrict__ W2,
    const float* __restrict__ b2, float* __restrict__ out)
{
    const int g   = blockIdx.x * 256 + threadIdx.x;
    const int row = g >> 2;     // batch row
    const int j   = g & 3;      // quad lane

    // Weights for this lane's units, ordered by DPP-arrival group:
    // group m supplies cols 4*(j^m)+k.  wl[m][k][u] = KSC*W1[col][hu],
    // 0-padded for hu>=10 (clamped address, zeroed value).
    float wl[4][4][UPL];
    float bl[UPL];
#pragma unroll
    for (int u = 0; u < UPL; ++u) {
        const int hu = UPL * j + u;
        const int hc = (hu < HS) ? hu : 0;
        const bool ok = (hu < HS);
        bl[u] = ok ? KSC * b1[hc] : 0.0f;
#pragma unroll
        for (int m = 0; m < 4; ++m) {
            const int lm = j ^ m;
#pragma unroll
            for (int k = 0; k < 4; ++k) {
                const int col = 4 * lm + k;
                wl[m][k][u] = ok ? KSC * W1[col * HS + hc] : 0.0f;
            }
        }
    }
#pragma unroll
    for (int m = 0; m < 4; ++m)
#pragma unroll
        for (int k = 0; k < 4; ++k)
#pragma unroll
            for (int u = 0; u < UPL; ++u) { PIN(wl[m][k][u]); }
#pragma unroll
    for (int u = 0; u < UPL; ++u) { PIN(bl[u]); }

    float h[UPL];
#pragma unroll
    for (int u = 0; u < UPL; ++u) h[u] = 0.0f;

    // lane j's float4 of step s: x[row][s][4j..4j+3]
    const f4v* __restrict__ xr =
        reinterpret_cast<const f4v*>(x) + (size_t)row * (SEQ * 4) + j;

    // depth-8 register prefetch (2 KB/wave/slot-set, 32 VGPRs)
    f4v buf[PFD];
#pragma unroll
    for (int r = 0; r < PFD; ++r)
        buf[r] = __builtin_nontemporal_load(xr + r * 4);

#define STEP(S, PF)                                                          \
    {                                                                        \
        const int slot = (S) & (PFD - 1);                                    \
        const f4v g0 = buf[slot];                                            \
        if (PF) buf[slot] = __builtin_nontemporal_load(xr + ((S) + PFD) * 4);\
        const f4v g1 = qp4<0xB1>(g0);                                        \
        const f4v g2 = qp4<0x4E>(g0);                                        \
        const f4v g3 = qp4<0x1B>(g0);                                        \
        _Pragma("unroll")                                                    \
        for (int u = 0; u < UPL; ++u) {                                      \
            /* 4 parallel FMA chains (depth 4) -> 2-level tree combine */    \
            float p0 = fmaf(g0.x, wl[0][0][u], bl[u]);                       \
            p0 = fmaf(g0.y, wl[0][1][u], p0);                                \
            p0 = fmaf(g0.z, wl[0][2][u], p0);                                \
            p0 = fmaf(g0.w, wl[0][3][u], p0);                                \
            float p1 = g1.x * wl[1][0][u];                                   \
            p1 = fmaf(g1.y, wl[1][1][u], p1);                                \
            p1 = fmaf(g1.z, wl[1][2][u], p1);                                \
            p1 = fmaf(g1.w, wl[1][3][u], p1);                                \
            float p2 = g2.x * wl[2][0][u];                                   \
            p2 = fmaf(g2.y, wl[2][1][u], p2);                                \
            p2 = fmaf(g2.z, wl[2][2][u], p2);                                \
            p2 = fmaf(g2.w, wl[2][3][u], p2);                                \
            float p3 = g3.x * wl[3][0][u];                                   \
            p3 = fmaf(g3.y, wl[3][1][u], p3);                                \
            p3 = fmaf(g3.z, wl[3][2][u], p3);                                \
            p3 = fmaf(g3.w, wl[3][3][u], p3);                                \
            const float aK = (p0 + p1) + (p2 + p3);   /* = KSC*(x@W1+b1) */  \
            /* tanh(h+a) = 1 - 2/(exp2(KSC*h + aK) + 1); rcp ~2-3ulp */      \
            const float e = __builtin_amdgcn_exp2f(fmaf(KSC, h[u], aK));     \
            h[u] = fmaf(-2.0f, __builtin_amdgcn_rcpf(e + 1.0f), 1.0f);       \
        }                                                                    \
    }

    // main loop: unconditional prefetch; tail: no prefetch (no clamp math)
#pragma unroll 8
    for (int s = 0; s < SEQ - PFD; ++s) STEP(s, true);
#pragma unroll
    for (int s = SEQ - PFD; s < SEQ; ++s) STEP(s, false);
#undef STEP

    // epilogue: y = sigmoid(h @ W2 + b2); partial over this lane's units,
    // then quad butterfly all-reduce via DPP (padded units have h==0).
    float y[OUTF];
#pragma unroll
    for (int o = 0; o < OUTF; ++o) y[o] = 0.0f;
#pragma unroll
    for (int u = 0; u < UPL; ++u) {
        const int hu = UPL * j + u;
        const float* w2r = W2 + (size_t)((hu < HS) ? hu : 0) * OUTF;
#pragma unroll
        for (int o = 0; o < OUTF; ++o)
            y[o] = fmaf(h[u], w2r[o], y[o]);
    }
#pragma unroll
    for (int o = 0; o < OUTF; ++o) y[o] += qp<0xB1>(y[o]);
#pragma unroll
    for (int o = 0; o < OUTF; ++o) y[o] += qp<0x4E>(y[o]);
#pragma unroll
    for (int o = 0; o < OUTF; ++o)
        y[o] = __builtin_amdgcn_rcpf(1.0f + __expf(-(y[o] + b2[o])));

    float* op = out + (size_t)row * OUTF;
    op[j] = y[j];
    if (j == 0) op[4] = y[4];
}

extern "C" void kernel_launch(void* const* d_in, const int* in_sizes, int n_in,
                              void* d_out, int out_size, void* d_ws, size_t ws_size,
                              hipStream_t stream) {
    const float* x  = (const float*)d_in[0];
    const float* W1 = (const float*)d_in[1];
    const float* b1 = (const float*)d_in[2];
    const float* W2 = (const float*)d_in[3];
    const float* b2 = (const float*)d_in[4];
    float* out = (float*)d_out;

    rnn_fused<<<(BATCH * 4) / 256, 256, 0, stream>>>(x, W1, b1, W2, b2, out);
}